// Round 16
// baseline (19092.857 us; speedup 1.0000x reference)
//
#include <hip/hip_runtime.h>
#include <hip/hip_bf16.h>

// LSTM: B=64, S=512, H=768, L=2. ROUND 16: LAYER-PIPELINED single dispatch.
// 512 WGs x 768 thr (2 blocks/CU): blocks 0-255 = layer0, 256-511 = layer1.
// Each block = round-8/11 skeleton (best measured: 6.55 ms/scan):
//   waves 0-5 (x): input projection one step ahead into 4-slot LDS ring.
//     L1 extra: x input = opk(s+1) (L0's h-stream) -> self-poll L0 flags >= s+2
//     (instant in steady state; L1 trails L0 by 2 steps).
//   waves 6-11 (h): wave6 polls own-layer flags; K=384 recurrent GEMM;
//     half1 waves finalize gates/state, bypass-store h, drain, flag.
// Deadlock-safe: L0 never waits on L1; in-order dispatch -> L0 resident first;
// worst case = sequential fallback. Sequential depth 1024 -> ~514 steps.
// h exchange: MALL-bypass relaxed-agent stores + vmcnt ack + per-WG flag;
// consumers plain cached loads on write-once streams (proven rounds 5-15).

#define HID 768
#define FH  3072
#define SEQ 512
#define BAT 64
#define GB  16           // batches per group
#define WPG 64           // workgroups per group
#define CPW 12           // h-columns per workgroup
#define NWG 256          // per layer
#define TPB 768          // 12 waves

typedef __attribute__((ext_vector_type(8))) __bf16 bf16x8;
typedef __attribute__((ext_vector_type(4))) float f32x4;
typedef unsigned int u32;

__device__ __forceinline__ float sigm(float z) { return 1.f / (1.f + __expf(-z)); }
__device__ __forceinline__ float tanh_fast(float x) {
  float a = fabsf(x);
  float e = __expf(-2.f * a);
  float t = (1.f - e) / (1.f + e);
  return copysignf(t, x);
}
__device__ __forceinline__ unsigned short bfbits(__bf16 b) {
  union { __bf16 b; unsigned short s; } u; u.b = b; return u.s;
}
__device__ __forceinline__ __bf16 bits2bf(unsigned short s) {
  union { unsigned short s; __bf16 b; } u; u.s = s; return u.b;
}
__device__ __forceinline__ u32 packsplit(float v) {
  __bf16 h = (__bf16)v;
  __bf16 l = (__bf16)(v - (float)h);
  return ((u32)bfbits(h) << 16) | (u32)bfbits(l);
}
__device__ __forceinline__ void split8(const float* p, bf16x8& hi, bf16x8& lo) {
  const float4* q = (const float4*)p;
  float4 a = q[0], b = q[1];
  float v[8] = {a.x, a.y, a.z, a.w, b.x, b.y, b.z, b.w};
#pragma unroll
  for (int i = 0; i < 8; ++i) {
    __bf16 h = (__bf16)v[i];
    hi[i] = h;
    lo[i] = (__bf16)(v[i] - (float)h);
  }
}
__device__ __forceinline__ void unpack8(const u32 w[8], bf16x8& hi, bf16x8& lo) {
#pragma unroll
  for (int i = 0; i < 8; ++i) {
    hi[i] = bits2bf((unsigned short)(w[i] >> 16));
    lo[i] = bits2bf((unsigned short)(w[i] & 0xffffu));
  }
}

// K=384 projection slice: 12 chunks x 3 MFMAs, returns summed D fragment.
template<int FMT>
__device__ __forceinline__ f32x4 proj384(const float* xf, const u32* xp,
                                         size_t base,
                                         const bf16x8* ah, const bf16x8* al) {
  f32x4 acc[4];
#pragma unroll
  for (int r = 0; r < 4; ++r) acc[r] = f32x4{0.f, 0.f, 0.f, 0.f};
#pragma unroll
  for (int kk = 0; kk < 12; ++kk) {
    bf16x8 bhi, blo;
    if constexpr (FMT == 0) {
      split8(xf + base + kk*32, bhi, blo);
    } else {
      const uint4* p = (const uint4*)(xp + base + kk*32);
      uint4 A = p[0], B = p[1];
      u32 w[8] = {A.x, A.y, A.z, A.w, B.x, B.y, B.z, B.w};
      unpack8(w, bhi, blo);
    }
    acc[(3*kk+0)&3] = __builtin_amdgcn_mfma_f32_16x16x32_bf16(ah[kk], bhi, acc[(3*kk+0)&3], 0, 0, 0);
    acc[(3*kk+1)&3] = __builtin_amdgcn_mfma_f32_16x16x32_bf16(al[kk], bhi, acc[(3*kk+1)&3], 0, 0, 0);
    acc[(3*kk+2)&3] = __builtin_amdgcn_mfma_f32_16x16x32_bf16(ah[kk], blo, acc[(3*kk+2)&3], 0, 0, 0);
  }
  return acc[0] + acc[1] + acc[2] + acc[3];
}

__attribute__((amdgpu_waves_per_eu(6, 6)))
__global__ void __launch_bounds__(TPB)
lstm_fused(const float* __restrict__ x,    // [64][512][768] fp32
           const float* __restrict__ mask, // [64][512]
           const float* __restrict__ Wih,  // [2][3072][768]
           const float* __restrict__ Whh,  // [2][3072][768]
           const float* __restrict__ bih,  // [2][3072]
           const float* __restrict__ bhh,
           u32* __restrict__ opk,          // L0 h-stream / L1 input [512][64][768]
           u32* __restrict__ hpk,          // L1 h-stream
           float* __restrict__ out_f,      // [64][512][768]
           float* __restrict__ hn,         // [2][64][768]
           float* __restrict__ cn,
           int* __restrict__ flags)        // [2][NWG], zeroed
{
  __shared__ f32x4 xacc_l[4][3][64];      // x-proj ring (12288 B)
  __shared__ f32x4 xpart_l[3][64];        // 3072 B
  __shared__ f32x4 hpart_l[2][3][64];     // 6144 B  (21504 B total)

  const int wg  = blockIdx.x;
  const bool LY1 = (wg >= NWG);
  const int lwg = wg & (NWG - 1);
  const int grp = lwg >> 6;
  const int wid = lwg & 63;
  const int tid = threadIdx.x;
  const int wv  = tid >> 6;        // 0..11
  const int l   = tid & 63;
  const int l15 = l & 15;
  const int lhi = l >> 4;

  const bool isx  = (wv < 6);
  const int lane6 = isx ? wv : (wv - 6);
  const int tile  = lane6 >> 1;    // 0..2
  const int half  = lane6 & 1;
  const int kofs  = half * 384;

  const size_t loff = LY1 ? (size_t)FH*HID : 0;
  const float* Wih_l = Wih + loff;
  const float* Whh_l = Whh + loff;
  const float* bih_l = bih + (LY1 ? FH : 0);
  const float* bhh_l = bhh + (LY1 ? FH : 0);
  u32* hstream = LY1 ? hpk : opk;            // own h-stream (write+recurrent read)
  int* gflags  = flags + (LY1 ? NWG : 0) + grp*WPG;   // own layer
  int* gflags0 = flags + grp*WPG;                     // L0 (for L1 x gating)

  // ---- weights (split-bf16) -> fragments (remat tolerated; round-8 proven)
  const int colA = wid*CPW + tile*4 + (l15 >> 2);
  const int qA   = l15 & 3;
  const float* wih_row = Wih_l + (size_t)(qA*HID + colA)*HID + kofs + lhi*8;
  const float* whh_row = Whh_l + (size_t)(qA*HID + colA)*HID + kofs + lhi*8;
  bf16x8 ah[12], al[12], ahh[12], alh[12];
#pragma unroll
  for (int kk = 0; kk < 12; ++kk) split8(wih_row + kk*32, ah[kk],  al[kk]);
#pragma unroll
  for (int kk = 0; kk < 12; ++kk) split8(whh_row + kk*32, ahh[kk], alh[kk]);

  const int batch = grp*GB + l15;
  const int colO  = wid*CPW + tile*4 + lhi;
  float bias4[4] = {0.f, 0.f, 0.f, 0.f};
  if (!isx && half == 1) {
#pragma unroll
    for (int r = 0; r < 4; ++r) bias4[r] = bih_l[r*HID + colO] + bhh_l[r*HID + colO];
  }
  const float* mrow = mask + batch*SEQ;
  const int kb = kofs + lhi*8;

  float cstate = 0.f;

  // ---- prologue: xacc(0) (L1 waits for L0 step 1) ----
  {
    f32x4 px{0.f, 0.f, 0.f, 0.f};
    if (isx) {
      if (LY1) {
        while (true) {
          int v = __hip_atomic_load(gflags0 + l, __ATOMIC_RELAXED, __HIP_MEMORY_SCOPE_AGENT);
          if (__all(v >= 1)) break;
          __builtin_amdgcn_s_sleep(4);
        }
        px = proj384<1>(nullptr, opk, ((size_t)batch)*HID + kb, ah, al);
      } else {
        px = proj384<0>(x, nullptr, ((size_t)batch*SEQ)*HID + kb, ah, al);
      }
      if (half == 0) xpart_l[tile][l] = px;
    }
    __syncthreads();
    if (isx && half == 1) xacc_l[0][tile][l] = px + xpart_l[tile][l];
    __syncthreads();
  }

#pragma unroll 1
  for (int s = 0; s < SEQ; ++s) {
    // ---- phase0: x-waves compute s+1 (L1 gates on L0 flags); wave6 polls own
    f32x4 xa{0.f, 0.f, 0.f, 0.f};
    if (isx && s + 1 < SEQ) {
      if (LY1) {
        while (true) {
          int v = __hip_atomic_load(gflags0 + l, __ATOMIC_RELAXED, __HIP_MEMORY_SCOPE_AGENT);
          if (__all(v >= s + 2)) break;
          __builtin_amdgcn_s_sleep(2);
        }
        xa = proj384<1>(nullptr, opk, ((size_t)(s+1)*BAT + batch)*HID + kb, ah, al);
      } else {
        xa = proj384<0>(x, nullptr, ((size_t)batch*SEQ + (s+1))*HID + kb, ah, al);
      }
      if (half == 0) xpart_l[tile][l] = xa;
    }
    if (!isx && lane6 == 0 && s > 0) {     // wave 6 polls own layer flags
      while (true) {
        int v = __hip_atomic_load(gflags + l, __ATOMIC_RELAXED, __HIP_MEMORY_SCOPE_AGENT);
        if (__all(v >= s)) break;
        __builtin_amdgcn_s_sleep(1);
      }
    }
    __syncthreads();   // b1

    // ---- phase1: h-waves K=384 GEMM on h(s-1); x half1 folds xacc(s+1) ----
    f32x4 ha{0.f, 0.f, 0.f, 0.f};
    if (!isx && s > 0) {
      ha = proj384<1>(nullptr, hstream, ((size_t)(s-1)*BAT + batch)*HID + kb, ahh, alh);
      if (half == 0) hpart_l[s & 1][tile][l] = ha;
    }
    if (isx && half == 1 && s + 1 < SEQ)
      xacc_l[(s+1) & 3][tile][l] = xa + xpart_l[tile][l];
    __syncthreads();   // b2

    // ---- phase2: finalize (h half1 waves) ----
    if (!isx && half == 1) {
      f32x4 z = xacc_l[s & 3][tile][l];
      if (s > 0) z = z + ha + hpart_l[s & 1][tile][l];
      float zi = z[0] + bias4[0], zf = z[1] + bias4[1];
      float zg = z[2] + bias4[2], zo = z[3] + bias4[3];
      float iv = sigm(zi), fv = sigm(zf), gv = tanh_fast(zg), ov = sigm(zo);
      float c  = fv*cstate + iv*gv;
      float hv = ov * tanh_fast(c);
      float m  = mrow[s];
      hv *= m; c *= m; cstate = c;

      u32 hw = packsplit(hv);
      __hip_atomic_store(hstream + ((size_t)s*BAT + batch)*HID + colO, hw,
                         __ATOMIC_RELAXED, __HIP_MEMORY_SCOPE_AGENT);
      if (LY1) {
        __builtin_nontemporal_store(hv, out_f + ((size_t)batch*SEQ + s)*HID + colO);
      }
      if (s == SEQ - 1) {
        float* hnl = hn + (LY1 ? 49152 : 0);
        float* cnl = cn + (LY1 ? 49152 : 0);
        hnl[batch*HID + colO] = hv;
        cnl[batch*HID + colO] = c;
      }
      asm volatile("s_waitcnt vmcnt(0)" ::: "memory");  // h at MALL before flag
    }
    __syncthreads();   // b3
    if (tid == 0)
      __hip_atomic_store(gflags + wid, s + 1,
                         __ATOMIC_RELAXED, __HIP_MEMORY_SCOPE_AGENT);
  }
}

extern "C" void kernel_launch(void* const* d_in, const int* in_sizes, int n_in,
                              void* d_out, int out_size, void* d_ws, size_t ws_size,
                              hipStream_t stream) {
  const float* x    = (const float*)d_in[0];
  const float* mask = (const float*)d_in[1];
  const float* Wih  = (const float*)d_in[2];
  const float* Whh  = (const float*)d_in[3];
  const float* bih  = (const float*)d_in[4];
  const float* bhh  = (const float*)d_in[5];
  float* out = (float*)d_out;

  char* ws = (char*)d_ws;
  const size_t STREAM_B = (size_t)SEQ * BAT * HID * sizeof(u32);  // 100,663,296
  u32* opk   = (u32*)(ws);                 // L0 h-stream = L1 input
  u32* hpk   = (u32*)(ws + STREAM_B);      // L1 h-stream
  int* flags = (int*)(ws + 2*STREAM_B);    // [2][NWG]

  (void)hipMemsetAsync(flags, 0, 2*NWG*sizeof(int), stream);

  float* hn = out + 25165824;              // [2][64][768]
  float* cn = out + 25165824 + 98304;

  lstm_fused<<<dim3(2*NWG), dim3(TPB), 0, stream>>>(
      x, mask, Wih, Whh, bih, bhh, opk, hpk, out, hn, cn, flags);
}

// Round 17
// 13122.604 us; speedup vs baseline: 1.4550x; 1.4550x over previous
//
#include <hip/hip_runtime.h>
#include <hip/hip_bf16.h>

// LSTM: B=64, S=512, H=768, L=2. ROUND 17: x-projection REMOVED from the scan.
// Per layer, per 64-step segment: [xproj GEMM] -> [slim scan].
//   xproj_gemm: 1024 WGs x 12 waves, tiles (grp,wid,sq); wave=(t,ks) K=192;
//               A-frags from pre-split wih_pk; 4-step accumulation; writes
//               packed hi|lo u32 xpk in scan-finalize layout.
//   lstm_scan:  256 WGs x 15 waves. waves 0-11: K=64 h-slices (48-VGPR
//               weights, 4-load volley, 18 MFMA) -> hpart LDS. waves 12-14:
//               prefetch xpk, wave12 polls flags, finalize after b2 (sum 12
//               hparts + xproj + gates), bypass-store h, drain, flag election.
//               2 barriers/step. 15 waves -> 4/SIMD -> 128-VGPR budget; LDS
//               padded >80KB to pin 1 block/CU.
// h exchange: MALL-bypass stores + vmcnt ack + per-WG flag; consumers plain
// cached loads on write-once streams (L0) / bypass ring (L1) - all proven.
// Cross-launch visibility via dispatch-boundary acquire/release (proven since
// round-5 pack_x->scan).

#define HID 768
#define FH  3072
#define SEQ 512
#define BAT 64
#define GB  16
#define SSEG 64
#define SEGS 8
#define NWG 256
#define STPB 960        // scan: 15 waves
#define GTPB 768        // gemm: 12 waves

typedef __attribute__((ext_vector_type(8))) __bf16 bf16x8;
typedef __attribute__((ext_vector_type(4))) float f32x4;
typedef unsigned int u32;
typedef unsigned long long u64;

__device__ __forceinline__ float sigm(float z) { return 1.f / (1.f + __expf(-z)); }
__device__ __forceinline__ float tanh_fast(float x) {
  float a = fabsf(x);
  float e = __expf(-2.f * a);
  float t = (1.f - e) / (1.f + e);
  return copysignf(t, x);
}
__device__ __forceinline__ unsigned short bfbits(__bf16 b) {
  union { __bf16 b; unsigned short s; } u; u.b = b; return u.s;
}
__device__ __forceinline__ __bf16 bits2bf(unsigned short s) {
  union { unsigned short s; __bf16 b; } u; u.s = s; return u.b;
}
__device__ __forceinline__ u32 packsplit(float v) {
  __bf16 h = (__bf16)v;
  __bf16 l = (__bf16)(v - (float)h);
  return ((u32)bfbits(h) << 16) | (u32)bfbits(l);
}
__device__ __forceinline__ float unpackf(u32 w) {
  return (float)bits2bf((unsigned short)(w >> 16)) +
         (float)bits2bf((unsigned short)(w & 0xffffu));
}
__device__ __forceinline__ void split8(const float* p, bf16x8& hi, bf16x8& lo) {
  const float4* q = (const float4*)p;
  float4 a = q[0], b = q[1];
  float v[8] = {a.x, a.y, a.z, a.w, b.x, b.y, b.z, b.w};
#pragma unroll
  for (int i = 0; i < 8; ++i) {
    __bf16 h = (__bf16)v[i];
    hi[i] = h;
    lo[i] = (__bf16)(v[i] - (float)h);
  }
}
__device__ __forceinline__ void unpack8(const u32 w[8], bf16x8& hi, bf16x8& lo) {
#pragma unroll
  for (int i = 0; i < 8; ++i) {
    hi[i] = bits2bf((unsigned short)(w[i] >> 16));
    lo[i] = bits2bf((unsigned short)(w[i] & 0xffffu));
  }
}
__device__ __forceinline__ bf16x8 q2b(uint4 q) {
  union { uint4 q; bf16x8 v; } u; u.q = q; return u.v;
}
__device__ __forceinline__ uint4 b2q(bf16x8 v) {
  union { bf16x8 v; uint4 q; } u; u.v = v; return u.q;
}

// ---- prep: pre-split weights ----
// wih slice (layer,wid,t,ks,c): sr = layer*4608 + wid*72 + t*24 + ks*6 + c,
//   k = ks*192 + c*32 + lhi*8.
// whh slice (layer,wid,j,t,c): sr = layer*4608 + wid*72 + j*6 + t*2 + c,
//   k = j*64 + c*32 + lhi*8.   (round-13 verified layout)
// row = (l15&3)*HID + wid*12 + t*4 + (l15>>2). 512 u32 per slice, lane*8.
__global__ void pack_w(const float* __restrict__ Wih,
                       const float* __restrict__ Whh,
                       u32* __restrict__ wpk) {
  int g = blockIdx.x * blockDim.x + threadIdx.x;
  const int NT = 2 * 9216 * 64;
  if (g >= NT) return;
  int lane = g & 63;
  int sl = g >> 6;
  int region = sl / 9216;          // 0 = wih, 1 = whh
  int sr = sl % 9216;
  int l15 = lane & 15, lhi = lane >> 4;
  int k, t, wid, layer;
  const float* W;
  if (region == 0) {
    int c  = sr % 6;
    int ks = (sr / 6) % 4;
    t      = (sr / 24) % 3;
    wid    = (sr / 72) % 64;
    layer  = sr / 4608;
    k = ks*192 + c*32 + lhi*8;
    W = Wih + (size_t)layer*FH*HID;
  } else {
    int c  = sr % 2;
    t      = (sr / 2) % 3;
    int j  = (sr / 6) % 12;
    wid    = (sr / 72) % 64;
    layer  = sr / 4608;
    k = j*64 + c*32 + lhi*8;
    W = Whh + (size_t)layer*FH*HID;
  }
  int row = (l15 & 3)*HID + wid*12 + t*4 + (l15 >> 2);
  bf16x8 hi, lo;
  split8(W + (size_t)row*HID + k, hi, lo);
  u32* dst = wpk + ((size_t)region*9216 + sr)*512 + lane*8;
  *(uint4*)dst       = b2q(hi);
  *(uint4*)(dst + 4) = b2q(lo);
}

#define MFMA16 __builtin_amdgcn_mfma_f32_16x16x32_bf16

// ---- xproj GEMM for one 64-step segment ----
// grid 1024: sq = wg&3, wid = (wg>>2)&63, grp = wg>>8. 12 waves: t=wv>>2, ks=wv&3.
template<int XFMT>
__global__ void __launch_bounds__(GTPB)
xproj_gemm(const float* __restrict__ xf,   // XFMT==0: x [64][512][768] fp32
           const u32* __restrict__ xp,     // XFMT==1: opk packed [512][64][768]
           const u32* __restrict__ wih_pk, // this layer's wih slices
           u32* __restrict__ xpk,          // out: segment buffer
           int s0)
{
  __shared__ f32x4 part[3][4][4][64];      // [t][ks][step4][lane] 49152 B

  const int wg  = blockIdx.x;
  const int sq  = wg & 3;
  const int wid = (wg >> 2) & 63;
  const int grp = wg >> 8;
  const int tid = threadIdx.x;
  const int wv  = tid >> 6;
  const int l   = tid & 63;
  const int l15 = l & 15;
  const int lhi = l >> 4;
  const int t   = wv >> 2;
  const int ks  = wv & 3;

  const int batch = grp*GB + l15;
  const u32* wb = wih_pk + (((size_t)(wid*3 + t)*4 + ks)*6)*512;

  uint4 wa[12];
#pragma unroll
  for (int c = 0; c < 6; ++c) {
    const uint4* wp = (const uint4*)(wb + (size_t)c*512 + l*8);
    wa[c*2]   = wp[0];
    wa[c*2+1] = wp[1];
  }

#pragma unroll 1
  for (int i0 = 0; i0 < 16; i0 += 4) {
    f32x4 acc[4];
#pragma unroll
    for (int i = 0; i < 4; ++i) acc[i] = f32x4{0.f, 0.f, 0.f, 0.f};
#pragma unroll
    for (int c = 0; c < 6; ++c) {
      int k = ks*192 + c*32 + lhi*8;
      bf16x8 Ah = q2b(wa[c*2]), Al = q2b(wa[c*2+1]);
#pragma unroll
      for (int i = 0; i < 4; ++i) {
        int sg = s0 + sq*16 + i0 + i;
        bf16x8 bhi, blo;
        if constexpr (XFMT == 0) {
          split8(xf + ((size_t)batch*SEQ + sg)*HID + k, bhi, blo);
        } else {
          const u32* sp = xp + ((size_t)sg*BAT + batch)*HID + k;
          uint4 A = *(const uint4*)sp, B = *(const uint4*)(sp + 4);
          u32 w[8] = {A.x, A.y, A.z, A.w, B.x, B.y, B.z, B.w};
          unpack8(w, bhi, blo);
        }
        acc[i] = MFMA16(Ah, bhi, acc[i], 0, 0, 0);
        acc[i] = MFMA16(Al, bhi, acc[i], 0, 0, 0);
        acc[i] = MFMA16(Ah, blo, acc[i], 0, 0, 0);
      }
    }
#pragma unroll
    for (int i = 0; i < 4; ++i) part[t][ks][i][l] = acc[i];
    __syncthreads();
    if (ks == 0) {
#pragma unroll
      for (int i = 0; i < 4; ++i) {
        f32x4 z = part[t][0][i][l] + part[t][1][i][l]
                + part[t][2][i][l] + part[t][3][i][l];
        int soff = sq*16 + i0 + i;
        u32* dst = xpk + ((size_t)((soff*4 + grp)*64 + wid)*3 + t)*256 + l*4;
        *(uint4*)dst = make_uint4(packsplit(z[0]), packsplit(z[1]),
                                  packsplit(z[2]), packsplit(z[3]));
      }
    }
    __syncthreads();
  }
}

// ---- slim scan for one 64-step segment ----
template<int LAYER>
__global__ void __launch_bounds__(STPB)
lstm_scan(const u32* __restrict__ xpk,     // segment xproj (packed)
          const float* __restrict__ mask,  // [64][512]
          const u32* __restrict__ whh_pk,  // this layer's whh slices
          const float* __restrict__ bih,   // this layer
          const float* __restrict__ bhh,
          u32* __restrict__ hdst,          // L0: stream [512][64][768]; L1: ring [2][64][768]
          const u32* __restrict__ hsrc,    // same buffer
          float* __restrict__ out_f,       // L1: [64][512][768]
          float* __restrict__ hn, float* __restrict__ cn,   // this layer
          float* __restrict__ cs,          // cstate scratch [64][768] f32
          int* __restrict__ flags,         // this layer: [4 groups][64]
          int s0)
{
  __shared__ f32x4 hpart[12][3][64];       // 36864 B
  __shared__ int lfin[SSEG];               // 256 B
  __shared__ f32x4 pad_lds[2816];          // 45056 B -> pins 1 block/CU

  const int wg  = blockIdx.x;
  const int grp = wg >> 6;
  const int wid = wg & 63;
  const int tid = threadIdx.x;
  const int wv  = tid >> 6;                // 0..14
  const int l   = tid & 63;
  const int l15 = l & 15;
  const int lhi = l >> 4;

  if ((int)blockIdx.x == -1) pad_lds[tid & 2047] = hpart[0][0][0];  // keep pad

  const bool ish   = (wv < 12);
  const bool isfin = (wv >= 12);
  const int  t     = wv - 12;              // finalize tile (valid when isfin)

  const int batch = grp*GB + l15;
  int* gflags = flags + grp*64;

  for (int i = tid; i < SSEG; i += STPB) lfin[i] = 0;

  // h-wave weights: 6 slices x (hi,lo) = 12 uint4 = 48 VGPRs
  uint4 wa[12];
  if (ish) {
    const u32* wbj = whh_pk + (size_t)(wid*12 + wv)*6*512;
#pragma unroll
    for (int tc = 0; tc < 6; ++tc) {       // tc = t*2 + c
      const uint4* wp = (const uint4*)(wbj + (size_t)tc*512 + l*8);
      wa[tc*2]   = wp[0];
      wa[tc*2+1] = wp[1];
    }
  }

  // finalize state
  const int colO = wid*12 + (isfin ? t : 0)*4 + lhi;
  float bias4[4] = {0.f, 0.f, 0.f, 0.f};
  float cstate = 0.f;
  if (isfin) {
#pragma unroll
    for (int r = 0; r < 4; ++r) bias4[r] = bih[r*HID + colO] + bhh[r*HID + colO];
    if (s0 > 0) cstate = cs[batch*HID + colO];
  }
  const float* mrow = mask + batch*SEQ;

  __syncthreads();   // lfin zeroed

#pragma unroll 1
  for (int s = s0; s < s0 + SSEG; ++s) {
    // ---- pre-b1: fin waves prefetch xproj; wave12 polls flags ----
    uint4 xq = make_uint4(0, 0, 0, 0);
    if (isfin) {
      xq = *(const uint4*)(xpk + ((size_t)(((s - s0)*4 + grp)*64 + wid)*3 + t)*256 + l*4);
      if (t == 0 && s > 0) {
        while (true) {
          int v = __hip_atomic_load(gflags + l, __ATOMIC_RELAXED, __HIP_MEMORY_SCOPE_AGENT);
          if (__all(v >= s)) break;
          __builtin_amdgcn_s_sleep(1);
        }
      }
    }
    __syncthreads();   // b1: h(s-1) globally readable

    // ---- h-waves: K=64 slice GEMM ----
    if (ish && s > 0) {
      f32x4 a0{0.f,0.f,0.f,0.f}, a1{0.f,0.f,0.f,0.f}, a2{0.f,0.f,0.f,0.f};
#pragma unroll
      for (int c = 0; c < 2; ++c) {
        int k = wv*64 + c*32 + lhi*8;
        u32 w[8];
        if constexpr (LAYER == 1) {
          const u64* sp = (const u64*)(hsrc + ((size_t)((s-1)&1)*BAT + batch)*HID + k);
          u64 qa = __hip_atomic_load(sp,   __ATOMIC_RELAXED, __HIP_MEMORY_SCOPE_AGENT);
          u64 qb = __hip_atomic_load(sp+1, __ATOMIC_RELAXED, __HIP_MEMORY_SCOPE_AGENT);
          u64 qc = __hip_atomic_load(sp+2, __ATOMIC_RELAXED, __HIP_MEMORY_SCOPE_AGENT);
          u64 qd = __hip_atomic_load(sp+3, __ATOMIC_RELAXED, __HIP_MEMORY_SCOPE_AGENT);
          w[0]=(u32)qa; w[1]=(u32)(qa>>32); w[2]=(u32)qb; w[3]=(u32)(qb>>32);
          w[4]=(u32)qc; w[5]=(u32)(qc>>32); w[6]=(u32)qd; w[7]=(u32)(qd>>32);
        } else {
          const u32* sp = hsrc + ((size_t)(s-1)*BAT + batch)*HID + k;
          uint4 A = *(const uint4*)sp, B = *(const uint4*)(sp + 4);
          w[0]=A.x; w[1]=A.y; w[2]=A.z; w[3]=A.w;
          w[4]=B.x; w[5]=B.y; w[6]=B.z; w[7]=B.w;
        }
        bf16x8 bhi, blo;
        unpack8(w, bhi, blo);
        {
          bf16x8 Ah = q2b(wa[(0*2+c)*2]), Al = q2b(wa[(0*2+c)*2+1]);
          a0 = MFMA16(Ah, bhi, a0, 0,0,0); a0 = MFMA16(Al, bhi, a0, 0,0,0); a0 = MFMA16(Ah, blo, a0, 0,0,0);
        }
        {
          bf16x8 Ah = q2b(wa[(1*2+c)*2]), Al = q2b(wa[(1*2+c)*2+1]);
          a1 = MFMA16(Ah, bhi, a1, 0,0,0); a1 = MFMA16(Al, bhi, a1, 0,0,0); a1 = MFMA16(Ah, blo, a1, 0,0,0);
        }
        {
          bf16x8 Ah = q2b(wa[(2*2+c)*2]), Al = q2b(wa[(2*2+c)*2+1]);
          a2 = MFMA16(Ah, bhi, a2, 0,0,0); a2 = MFMA16(Al, bhi, a2, 0,0,0); a2 = MFMA16(Ah, blo, a2, 0,0,0);
        }
      }
      hpart[wv][0][l] = a0;
      hpart[wv][1][l] = a1;
      hpart[wv][2][l] = a2;
    }
    __syncthreads();   // b2: hpart ready

    // ---- finalize (waves 12-14) ----
    if (isfin) {
      f32x4 z = f32x4{unpackf(xq.x), unpackf(xq.y), unpackf(xq.z), unpackf(xq.w)};
      if (s > 0) {
#pragma unroll
        for (int j = 0; j < 12; ++j) z = z + hpart[j][t][l];
      }
      float zi = z[0] + bias4[0], zf = z[1] + bias4[1];
      float zg = z[2] + bias4[2], zo = z[3] + bias4[3];
      float iv = sigm(zi), fv = sigm(zf), gv = tanh_fast(zg), ov = sigm(zo);
      float c  = fv*cstate + iv*gv;
      float hv = ov * tanh_fast(c);
      float m  = mrow[s];
      hv *= m; c *= m; cstate = c;

      u32 hw = packsplit(hv);
      size_t wrow = (LAYER == 1) ? ((size_t)(s & 1)*BAT + batch)*HID + colO
                                 : ((size_t)s*BAT + batch)*HID + colO;
      __hip_atomic_store(hdst + wrow, hw,
                         __ATOMIC_RELAXED, __HIP_MEMORY_SCOPE_AGENT);
      if constexpr (LAYER == 1) {
        __builtin_nontemporal_store(hv, out_f + ((size_t)batch*SEQ + s)*HID + colO);
      }
      if (s == SEQ - 1) {
        hn[batch*HID + colO] = hv;
        cn[batch*HID + colO] = c;
      }
      if (s == s0 + SSEG - 1) cs[batch*HID + colO] = cstate;
      asm volatile("s_waitcnt vmcnt(0)" ::: "memory");   // h at MALL
      if (l == 0) {
        int old = atomicAdd(&lfin[s - s0], 1);
        if (old == 2)    // last of the 3 finalize waves
          __hip_atomic_store(gflags + wid, s + 1,
                             __ATOMIC_RELAXED, __HIP_MEMORY_SCOPE_AGENT);
      }
    }
  }
}

extern "C" void kernel_launch(void* const* d_in, const int* in_sizes, int n_in,
                              void* d_out, int out_size, void* d_ws, size_t ws_size,
                              hipStream_t stream) {
  const float* x    = (const float*)d_in[0];
  const float* mask = (const float*)d_in[1];
  const float* Wih  = (const float*)d_in[2];
  const float* Whh  = (const float*)d_in[3];
  const float* bih  = (const float*)d_in[4];
  const float* bhh  = (const float*)d_in[5];
  float* out = (float*)d_out;

  char* ws = (char*)d_ws;
  const size_t WPK_B  = (size_t)2*9216*512*4;        // 37,748,736
  const size_t XPK_B  = (size_t)SSEG*BAT*FH*4;       // 50,331,648
  const size_t STRM_B = (size_t)SEQ*BAT*HID*4;       // 100,663,296
  const size_t RING_B = (size_t)2*BAT*HID*4;         // 393,216
  const size_t CS_B   = (size_t)2*BAT*HID*4;         // 393,216

  u32* wpk  = (u32*)ws;
  u32* xpk  = (u32*)(ws + WPK_B);
  u32* opk  = (u32*)(ws + WPK_B + XPK_B);            // L0 h-stream = L1 GEMM input
  u32* ring = (u32*)(ws + WPK_B + XPK_B + STRM_B);   // L1 recurrence ring
  float* cs = (float*)(ws + WPK_B + XPK_B + STRM_B + RING_B);
  int* flags = (int*)(ws + WPK_B + XPK_B + STRM_B + RING_B + CS_B);
  // flags: [2 layers][4 groups][64]

  (void)hipMemsetAsync(flags, 0, 2*4*64*sizeof(int), stream);
  pack_w<<<4608, 256, 0, stream>>>(Wih, Whh, wpk);

  float* hn = out + 25165824;                        // [2][64][768]
  float* cn = out + 25165824 + 98304;

  const u32* wih0 = wpk;
  const u32* wih1 = wpk + (size_t)4608*512;
  const u32* whh0 = wpk + (size_t)9216*512;
  const u32* whh1 = wpk + (size_t)13824*512;

  // ---- layer 0: GEMM(x) + slim scan per segment ----
  for (int seg = 0; seg < SEGS; ++seg) {
    int s0 = seg * SSEG;
    xproj_gemm<0><<<dim3(1024), dim3(GTPB), 0, stream>>>(
        x, nullptr, wih0, xpk, s0);
    lstm_scan<0><<<dim3(NWG), dim3(STPB), 0, stream>>>(
        xpk, mask, whh0, bih, bhh,
        opk, opk, nullptr, hn, cn, cs, flags, s0);
  }
  // ---- layer 1: GEMM(h0) + slim scan per segment ----
  for (int seg = 0; seg < SEGS; ++seg) {
    int s0 = seg * SSEG;
    xproj_gemm<1><<<dim3(1024), dim3(GTPB), 0, stream>>>(
        nullptr, opk, wih1, xpk, s0);
    lstm_scan<1><<<dim3(NWG), dim3(STPB), 0, stream>>>(
        xpk, mask, whh1, bih + FH, bhh + FH,
        ring, ring, out, hn + 49152, cn + 49152, cs + 49152, flags + 4*64, s0);
  }
}